// Round 3
// baseline (2299.792 us; speedup 1.0000x reference)
//
#include <hip/hip_runtime.h>
#include <math.h>

#define BATCH 256
#define CIN 1280
#define COUT 128
#define F1IN 6272
#define F1OUT 4096
#define F2OUT 1470
#define NBOX 98

// ---------------------------------------------------------------------------
// Stage 1: subsample + 1x1 conv as GEMM.  h1[b, o*49+s] = sum_c x[b,c,2i,2j]*w[o,c] + bias[o]
// v2: xs staged as double (converts each element once instead of 64x in the
//     inner loop), wT padded to 65 (kills 64-way LDS write bank conflict),
//     c-chunk 64 to fit LDS (25.1K + 16.6K = 41.7KB -> 3 blocks/CU cap).
// ---------------------------------------------------------------------------
__global__ __launch_bounds__(256) void conv_kernel(const float* __restrict__ x,
                                                   const float* __restrict__ w,
                                                   const float* __restrict__ bias,
                                                   double* __restrict__ h1) {
    const int b = blockIdx.x;
    const int obase = blockIdx.y * 64;
    const int tid = threadIdx.x;
    const int o_l = tid & 63;
    const int g = tid >> 6;          // 0..3, strided s coverage

    __shared__ double xs[64 * 49];   // [c][s] chunk, pre-converted to double
    __shared__ float wT[64 * 65];    // [c][o] chunk, +1 pad breaks bank conflict

    double acc[13];
#pragma unroll
    for (int k = 0; k < 13; ++k) acc[k] = 0.0;

    const float* xb = x + (size_t)b * CIN * 196;

    for (int cb = 0; cb < CIN; cb += 64) {
        __syncthreads();
        for (int idx = tid; idx < 64 * 49; idx += 256) {
            int c = idx / 49, s = idx - c * 49;
            int si = s / 7, sj = s - si * 7;
            xs[idx] = (double)xb[(size_t)(cb + c) * 196 + si * 28 + sj * 2];
        }
        for (int idx = tid; idx < 64 * 64; idx += 256) {
            int o = idx >> 6, c = idx & 63;   // consecutive tid -> consecutive c: coalesced read
            wT[c * 65 + o] = w[(size_t)(obase + o) * CIN + cb + c];
        }
        __syncthreads();
        for (int c = 0; c < 64; ++c) {
            double wv = (double)wT[c * 65 + o_l];
#pragma unroll
            for (int k = 0; k < 13; ++k) {
                int sg = g + 4 * k;
                if (sg < 49) acc[k] = fma(wv, xs[c * 49 + sg], acc[k]);
            }
        }
    }

    const int o = obase + o_l;
    const double bv = (double)bias[o];
    for (int k = 0; k < 13; ++k) {
        int sg = g + 4 * k;
        if (sg < 49) h1[(size_t)b * F1IN + (size_t)o * 49 + sg] = acc[k] + bv;
    }
}

// ---------------------------------------------------------------------------
// FC GEMM split-K (NT): partial C[m][n] += sum_{k in chunk} A[m][k]*W[n][k]
// A: double MxK row-major, W: float NxK row-major. C pre-zeroed; fp64 atomicAdd.
// v2: 64x64 tile, 128 threads, 4x8 micro (LDS bytes/FLOP 1.5 -> 1.0).
//     AFUSE folds FC1's bias+leaky into FC2's A-staging (drops a full RMW pass).
// v3: Ws staged as DOUBLE — converts W once at staging (2048 cvt/block/chunk)
//     instead of per-use in the inner loop (32768/block/chunk). Removes 8
//     v_cvt_f64_f32 per kk per thread = 25% of inner-loop VALU issue slots.
//     Bit-identical numerics (cvt is exact, merely relocated).
//     LDS 33.8KB -> still 4 blocks/CU.
// ---------------------------------------------------------------------------
template <bool NCHECK, bool AFUSE>
__global__ __launch_bounds__(128) void fc_splitk_kernel(const double* __restrict__ A,
                                                        const float* __restrict__ W,
                                                        const float* __restrict__ abias,
                                                        double* __restrict__ C,
                                                        int N, int K, int kchunks_per_slice) {
    __shared__ double As[64][33];
    __shared__ double Ws[64][33];

    const int mbase = blockIdx.x * 64;
    const int nbase = blockIdx.y * 64;
    const int kb0 = blockIdx.z * kchunks_per_slice * 32;
    const int kb1 = kb0 + kchunks_per_slice * 32;
    const int tid = threadIdx.x;
    const int tm = tid >> 3;   // 0..15 -> rows tm*4 + i
    const int tn = tid & 7;    // 0..7  -> cols tn*8 + j

    double acc[4][8];
#pragma unroll
    for (int i = 0; i < 4; ++i)
#pragma unroll
        for (int j = 0; j < 8; ++j) acc[i][j] = 0.0;

    for (int kb = kb0; kb < kb1; kb += 32) {
        __syncthreads();
        for (int idx = tid; idx < 64 * 32; idx += 128) {
            int r = idx >> 5, kk = idx & 31;
            double v = A[(size_t)(mbase + r) * K + kb + kk];
            if (AFUSE) {
                v += (double)abias[kb + kk];
                v = (v >= 0.0) ? v : 0.1 * v;
            }
            As[r][kk] = v;
        }
        for (int idx = tid; idx < 64 * 32; idx += 128) {
            int r = idx >> 5, kk = idx & 31;
            int n = nbase + r;
            Ws[r][kk] = (!NCHECK || n < N) ? (double)W[(size_t)n * K + kb + kk] : 0.0;
        }
        __syncthreads();
        for (int kk = 0; kk < 32; ++kk) {
            double a[4];
            double bw[8];
#pragma unroll
            for (int i = 0; i < 4; ++i) a[i] = As[tm * 4 + i][kk];
#pragma unroll
            for (int j = 0; j < 8; ++j) bw[j] = Ws[tn * 8 + j][kk];
#pragma unroll
            for (int i = 0; i < 4; ++i)
#pragma unroll
                for (int j = 0; j < 8; ++j)
                    acc[i][j] = fma(a[i], bw[j], acc[i][j]);
        }
    }

#pragma unroll
    for (int i = 0; i < 4; ++i) {
        int m = mbase + tm * 4 + i;
#pragma unroll
        for (int j = 0; j < 8; ++j) {
            int n = nbase + tn * 8 + j;
            if (!NCHECK || n < N)
                atomicAdd(&C[(size_t)m * N + n], acc[i][j]);
        }
    }
}

// ---------------------------------------------------------------------------
// Stage 4: fc2 bias + sigmoid + decode + stable sort + greedy NMS + top-10.
// One block / image. v2: fc2 bias folded in here (drops bias_act pass).
// ---------------------------------------------------------------------------
__global__ __launch_bounds__(128) void decode_nms_kernel(const double* __restrict__ Z,
                                                         const float* __restrict__ fc2b,
                                                         float* __restrict__ out_boxes,
                                                         float* __restrict__ out_labels,
                                                         float* __restrict__ out_confs) {
    const int b = blockIdx.x;
    const int tid = threadIdx.x;

    __shared__ double sAll[F2OUT];
    __shared__ double bx[NBOX][4];
    __shared__ double cf[NBOX];
    __shared__ int lab[NBOX];
    __shared__ double sbx[NBOX][4];
    __shared__ double scf[NBOX];
    __shared__ int slab[NBOX];
    __shared__ unsigned long long suprow[NBOX][2];

    const double* z = Z + (size_t)b * F2OUT;
    for (int i = tid; i < F2OUT; i += 128) {
        double v = z[i] + (double)fc2b[i];
        sAll[i] = 1.0 / (1.0 + exp(-v));
    }
    __syncthreads();

    // decode 98 boxes + labels
    for (int n = tid; n < NBOX; n += 128) {
        int gi = n / 14;
        int gj = (n % 14) >> 1;
        double cx = sAll[4 * n + 0] * 64.0 + 64.0 * (double)gi;
        double cy = sAll[4 * n + 1] * 64.0 + 64.0 * (double)gj;
        double w  = sAll[4 * n + 2] * 448.0;
        double hh = sAll[4 * n + 3] * 448.0;
        double x1 = cx - 0.5 * w,  y1 = cy - 0.5 * hh;
        double x2 = cx + 0.5 * w,  y2 = cy + 0.5 * hh;
        x1 = x1 < 0.0 ? 0.0 : (x1 > 448.0 ? 448.0 : x1);
        y1 = y1 < 0.0 ? 0.0 : (y1 > 448.0 ? 448.0 : y1);
        x2 = x2 < 0.0 ? 0.0 : (x2 > 448.0 ? 448.0 : x2);
        y2 = y2 < 0.0 ? 0.0 : (y2 > 448.0 ? 448.0 : y2);
        bx[n][0] = x1; bx[n][1] = y1; bx[n][2] = x2; bx[n][3] = y2;
        cf[n] = sAll[392 + n];
        int cell = n >> 1;
        double best = sAll[490 + cell * 20];
        int bl = 0;
        for (int c = 1; c < 20; ++c) {
            double v = sAll[490 + cell * 20 + c];
            if (v > best) { best = v; bl = c; }
        }
        lab[n] = bl;
    }
    __syncthreads();

    // stable descending sort by conf via rank counting
    for (int n = tid; n < NBOX; n += 128) {
        double cn = cf[n];
        int r = 0;
        for (int m = 0; m < NBOX; ++m) {
            double cm = cf[m];
            if (cm > cn || (cm == cn && m < n)) ++r;
        }
        scf[r] = cn;
        slab[r] = lab[n];
        sbx[r][0] = bx[n][0]; sbx[r][1] = bx[n][1];
        sbx[r][2] = bx[n][2]; sbx[r][3] = bx[n][3];
    }
    __syncthreads();

    // iou > 0.7 bitmask rows
    for (int i = tid; i < NBOX; i += 128) {
        double x1 = sbx[i][0], y1 = sbx[i][1], x2 = sbx[i][2], y2 = sbx[i][3];
        double ai = fmax(x2 - x1, 0.0) * fmax(y2 - y1, 0.0);
        unsigned long long m0 = 0ull, m1 = 0ull;
        for (int j = 0; j < NBOX; ++j) {
            double jx1 = sbx[j][0], jy1 = sbx[j][1], jx2 = sbx[j][2], jy2 = sbx[j][3];
            double xx1 = fmax(x1, jx1), yy1 = fmax(y1, jy1);
            double xx2 = fmin(x2, jx2), yy2 = fmin(y2, jy2);
            double inter = fmax(xx2 - xx1, 0.0) * fmax(yy2 - yy1, 0.0);
            double aj = fmax(jx2 - jx1, 0.0) * fmax(jy2 - jy1, 0.0);
            double uni = ai + aj - inter;
            double iou = (uni > 0.0) ? inter / uni : 0.0;
            if (iou > 0.7) {
                if (j < 64) m0 |= 1ull << j;
                else        m1 |= 1ull << (j - 64);
            }
        }
        suprow[i][0] = m0;
        suprow[i][1] = m1;
    }
    __syncthreads();

    if (tid == 0) {
        unsigned long long k0 = 0ull, k1 = 0ull;
        for (int i = 0; i < NBOX; ++i) {
            if (scf[i] > 0.1) {
                if (i < 64) k0 |= 1ull << i;
                else        k1 |= 1ull << (i - 64);
            }
        }
        for (int i = 0; i < NBOX; ++i) {
            bool ki = (i < 64) ? ((k0 >> i) & 1ull) : ((k1 >> (i - 64)) & 1ull);
            if (!ki) continue;
            unsigned long long g0, g1;
            if (i < 63)       { g0 = (~0ull) << (i + 1); g1 = ~0ull; }
            else if (i == 63) { g0 = 0ull;               g1 = ~0ull; }
            else              { g0 = 0ull;               g1 = (~0ull) << (i - 63); }
            k0 &= ~(suprow[i][0] & g0);
            k1 &= ~(suprow[i][1] & g1);
        }
        int cnt = 0;
        for (int i = 0; i < NBOX && cnt < 10; ++i) {
            bool ki = (i < 64) ? ((k0 >> i) & 1ull) : ((k1 >> (i - 64)) & 1ull);
            if (!ki) continue;
            out_boxes[(size_t)b * 40 + cnt * 4 + 0] = (float)sbx[i][0];
            out_boxes[(size_t)b * 40 + cnt * 4 + 1] = (float)sbx[i][1];
            out_boxes[(size_t)b * 40 + cnt * 4 + 2] = (float)sbx[i][2];
            out_boxes[(size_t)b * 40 + cnt * 4 + 3] = (float)sbx[i][3];
            out_labels[b * 10 + cnt] = (float)slab[i];
            out_confs[b * 10 + cnt]  = (float)scf[i];
            ++cnt;
        }
        for (; cnt < 10; ++cnt) {
            out_boxes[(size_t)b * 40 + cnt * 4 + 0] = 0.0f;
            out_boxes[(size_t)b * 40 + cnt * 4 + 1] = 0.0f;
            out_boxes[(size_t)b * 40 + cnt * 4 + 2] = 0.0f;
            out_boxes[(size_t)b * 40 + cnt * 4 + 3] = 0.0f;
            out_labels[b * 10 + cnt] = 0.0f;
            out_confs[b * 10 + cnt]  = 0.0f;
        }
    }
}

extern "C" void kernel_launch(void* const* d_in, const int* in_sizes, int n_in,
                              void* d_out, int out_size, void* d_ws, size_t ws_size,
                              hipStream_t stream) {
    const float* x      = (const float*)d_in[0];
    const float* conv_w = (const float*)d_in[1];
    const float* conv_b = (const float*)d_in[2];
    const float* fc1_w  = (const float*)d_in[3];
    const float* fc1_b  = (const float*)d_in[4];
    const float* fc2_w  = (const float*)d_in[5];
    const float* fc2_b  = (const float*)d_in[6];

    double* h1 = (double*)d_ws;                       // 256 x 6272
    double* a1 = h1 + (size_t)BATCH * F1IN;           // 256 x 4096 (raw fc1 sums, no bias)
    double* a2 = a1 + (size_t)BATCH * F1OUT;          // 256 x 1470 (raw fc2 sums, no bias)

    float* out_boxes  = (float*)d_out;                // 256*10*4
    float* out_labels = out_boxes + (size_t)BATCH * 40;   // 256*10
    float* out_confs  = out_labels + (size_t)BATCH * 10;  // 256*10

    // zero the atomic-accumulated outputs (graph-capture-legal)
    hipMemsetAsync(a1, 0, (size_t)BATCH * F1OUT * sizeof(double), stream);
    hipMemsetAsync(a2, 0, (size_t)BATCH * F2OUT * sizeof(double), stream);

    conv_kernel<<<dim3(BATCH, 2), 256, 0, stream>>>(x, conv_w, conv_b, h1);

    // FC1: M=256,N=4096,K=6272 -> 196 k-chunks, split 4 ways (49 each) = 1024 blocks
    fc_splitk_kernel<false, false><<<dim3(4, 64, 4), 128, 0, stream>>>(h1, fc1_w, nullptr, a1, F1OUT, F1IN, 49);

    // FC2: M=256,N=1470,K=4096 -> 128 k-chunks, split 8 ways (16 each) = 736 blocks
    // fc1 bias + leaky fused into A-staging
    fc_splitk_kernel<true, true><<<dim3(4, 23, 8), 128, 0, stream>>>(a1, fc2_w, fc1_b, a2, F2OUT, F1OUT, 16);

    // fc2 bias fused into decode's sigmoid
    decode_nms_kernel<<<BATCH, 128, 0, stream>>>(a2, fc2_b, out_boxes, out_labels, out_confs);
}

// Round 5
// 1462.468 us; speedup vs baseline: 1.5725x; 1.5725x over previous
//
#include <hip/hip_runtime.h>
#include <math.h>

#define BATCH 256
#define CIN 1280
#define COUT 128
#define F1IN 6272
#define F1OUT 4096
#define F2OUT 1470
#define NBOX 98

// ---------------------------------------------------------------------------
// Stage 1: subsample + 1x1 conv as GEMM.  h1[b, o*49+s] = sum_c x[b,c,2i,2j]*w[o,c] + bias[o]
// v4: o-tile 32 (grid 256x4 = 1024 blocks -> 4 blocks/CU, 16 waves/CU vs 8),
//     LDS 33.5KB. xs staged as double; wT [64][33] float, writes 2-way, reads
//     broadcast/conflict-free.
// ---------------------------------------------------------------------------
__global__ __launch_bounds__(256) void conv_kernel(const float* __restrict__ x,
                                                   const float* __restrict__ w,
                                                   const float* __restrict__ bias,
                                                   double* __restrict__ h1) {
    const int b = blockIdx.x;
    const int obase = blockIdx.y * 32;
    const int tid = threadIdx.x;
    const int o_l = tid & 31;        // 0..31
    const int g = tid >> 5;          // 0..7, strided s coverage

    __shared__ double xs[64 * 49];   // [c][s] chunk, pre-converted to double
    __shared__ float wT[64 * 33];    // [c][o] chunk, +1 pad

    double acc[7];
#pragma unroll
    for (int k = 0; k < 7; ++k) acc[k] = 0.0;

    const float* xb = x + (size_t)b * CIN * 196;

    for (int cb = 0; cb < CIN; cb += 64) {
        __syncthreads();
        for (int idx = tid; idx < 64 * 49; idx += 256) {
            int c = idx / 49, s = idx - c * 49;
            int si = s / 7, sj = s - si * 7;
            xs[idx] = (double)xb[(size_t)(cb + c) * 196 + si * 28 + sj * 2];
        }
        for (int idx = tid; idx < 64 * 32; idx += 256) {
            int o = idx >> 6, c = idx & 63;   // consecutive tid -> consecutive c: coalesced read
            wT[c * 33 + o] = w[(size_t)(obase + o) * CIN + cb + c];
        }
        __syncthreads();
        for (int c = 0; c < 64; ++c) {
            double wv = (double)wT[c * 33 + o_l];
#pragma unroll
            for (int k = 0; k < 7; ++k) {
                int sg = g + 8 * k;
                if (sg < 49) acc[k] = fma(wv, xs[c * 49 + sg], acc[k]);
            }
        }
    }

    const int o = obase + o_l;
    const double bv = (double)bias[o];
    for (int k = 0; k < 7; ++k) {
        int sg = g + 8 * k;
        if (sg < 49) h1[(size_t)b * F1IN + (size_t)o * 49 + sg] = acc[k] + bv;
    }
}

// ---------------------------------------------------------------------------
// FC GEMM split-K (NT): partial C[m][n] += sum_{k in chunk} A[m][k]*W[n][k]
// A: double MxK row-major, W: float NxK row-major. C pre-zeroed; fp64 atomicAdd.
// v4 (counter-driven redesign; v3 measured 20% VALU, 22% occ, 1.8e8 conflicts):
//   - kk-major LDS [16][66] (pad+2): inner reads are same-row broadcasts;
//     A-frag 4 distinct addrs (16-lane broadcast), W-frag 16 distinct addrs
//     covering all 32 banks -> conflict-free. Staging writes ~4-way (13% of
//     LDS traffic, acceptable).
//   - strided fragments rows tm+16i / cols tn+16j (bijective over 64x64 tile).
//   - 256 threads, micro 4x4, BK=16, LDS 16.9KB -> 9 blocks/CU cap;
//     grid z=8 (FC1) / z=16 (FC2) -> 8 / ~6 blocks/CU -> 32 / 23 waves/CU.
//   - cycle budget/wave/kk: 16 fma_f64 (64 cyc) vs 8 ds_read_b64 (~40 cyc)
//     -> FMA-bound with margin.
// ---------------------------------------------------------------------------
template <bool NCHECK, bool AFUSE>
__global__ __launch_bounds__(256) void fc_splitk_kernel(const double* __restrict__ A,
                                                        const float* __restrict__ W,
                                                        const float* __restrict__ abias,
                                                        double* __restrict__ C,
                                                        int N, int K, int kchunks_per_slice) {
    __shared__ double As2[16][66];
    __shared__ double Ws2[16][66];

    const int mbase = blockIdx.x * 64;
    const int nbase = blockIdx.y * 64;
    const int kb0 = blockIdx.z * kchunks_per_slice * 16;
    const int kb1 = kb0 + kchunks_per_slice * 16;
    const int tid = threadIdx.x;
    const int tm = tid >> 4;   // 0..15 -> rows tm + 16*i
    const int tn = tid & 15;   // 0..15 -> cols tn + 16*j

    double acc[4][4];
#pragma unroll
    for (int i = 0; i < 4; ++i)
#pragma unroll
        for (int j = 0; j < 4; ++j) acc[i][j] = 0.0;

    for (int kb = kb0; kb < kb1; kb += 16) {
        __syncthreads();
        // stage A (64 rows x 16 kk), kk-major
        for (int idx = tid; idx < 64 * 16; idx += 256) {
            int r = idx >> 4, kk = idx & 15;
            double v = A[(size_t)(mbase + r) * K + kb + kk];
            if (AFUSE) {
                v += (double)abias[kb + kk];
                v = (v >= 0.0) ? v : 0.1 * v;
            }
            As2[kk][r] = v;
        }
        // stage W (64 cols x 16 kk), kk-major, cvt once
        for (int idx = tid; idx < 64 * 16; idx += 256) {
            int c = idx >> 4, kk = idx & 15;
            int n = nbase + c;
            Ws2[kk][c] = (!NCHECK || n < N) ? (double)W[(size_t)n * K + kb + kk] : 0.0;
        }
        __syncthreads();
        for (int kk = 0; kk < 16; ++kk) {
            double a[4];
            double bw[4];
#pragma unroll
            for (int i = 0; i < 4; ++i) a[i] = As2[kk][tm + 16 * i];
#pragma unroll
            for (int j = 0; j < 4; ++j) bw[j] = Ws2[kk][tn + 16 * j];
#pragma unroll
            for (int i = 0; i < 4; ++i)
#pragma unroll
                for (int j = 0; j < 4; ++j)
                    acc[i][j] = fma(a[i], bw[j], acc[i][j]);
        }
    }

#pragma unroll
    for (int i = 0; i < 4; ++i) {
        int m = mbase + tm + 16 * i;
#pragma unroll
        for (int j = 0; j < 4; ++j) {
            int n = nbase + tn + 16 * j;
            if (!NCHECK || n < N)
                atomicAdd(&C[(size_t)m * N + n], acc[i][j]);
        }
    }
}

// ---------------------------------------------------------------------------
// Stage 4: fc2 bias + sigmoid + decode + stable sort + greedy NMS + top-10.
// One block / image. (unchanged)
// ---------------------------------------------------------------------------
__global__ __launch_bounds__(128) void decode_nms_kernel(const double* __restrict__ Z,
                                                         const float* __restrict__ fc2b,
                                                         float* __restrict__ out_boxes,
                                                         float* __restrict__ out_labels,
                                                         float* __restrict__ out_confs) {
    const int b = blockIdx.x;
    const int tid = threadIdx.x;

    __shared__ double sAll[F2OUT];
    __shared__ double bx[NBOX][4];
    __shared__ double cf[NBOX];
    __shared__ int lab[NBOX];
    __shared__ double sbx[NBOX][4];
    __shared__ double scf[NBOX];
    __shared__ int slab[NBOX];
    __shared__ unsigned long long suprow[NBOX][2];

    const double* z = Z + (size_t)b * F2OUT;
    for (int i = tid; i < F2OUT; i += 128) {
        double v = z[i] + (double)fc2b[i];
        sAll[i] = 1.0 / (1.0 + exp(-v));
    }
    __syncthreads();

    // decode 98 boxes + labels
    for (int n = tid; n < NBOX; n += 128) {
        int gi = n / 14;
        int gj = (n % 14) >> 1;
        double cx = sAll[4 * n + 0] * 64.0 + 64.0 * (double)gi;
        double cy = sAll[4 * n + 1] * 64.0 + 64.0 * (double)gj;
        double w  = sAll[4 * n + 2] * 448.0;
        double hh = sAll[4 * n + 3] * 448.0;
        double x1 = cx - 0.5 * w,  y1 = cy - 0.5 * hh;
        double x2 = cx + 0.5 * w,  y2 = cy + 0.5 * hh;
        x1 = x1 < 0.0 ? 0.0 : (x1 > 448.0 ? 448.0 : x1);
        y1 = y1 < 0.0 ? 0.0 : (y1 > 448.0 ? 448.0 : y1);
        x2 = x2 < 0.0 ? 0.0 : (x2 > 448.0 ? 448.0 : x2);
        y2 = y2 < 0.0 ? 0.0 : (y2 > 448.0 ? 448.0 : y2);
        bx[n][0] = x1; bx[n][1] = y1; bx[n][2] = x2; bx[n][3] = y2;
        cf[n] = sAll[392 + n];
        int cell = n >> 1;
        double best = sAll[490 + cell * 20];
        int bl = 0;
        for (int c = 1; c < 20; ++c) {
            double v = sAll[490 + cell * 20 + c];
            if (v > best) { best = v; bl = c; }
        }
        lab[n] = bl;
    }
    __syncthreads();

    // stable descending sort by conf via rank counting
    for (int n = tid; n < NBOX; n += 128) {
        double cn = cf[n];
        int r = 0;
        for (int m = 0; m < NBOX; ++m) {
            double cm = cf[m];
            if (cm > cn || (cm == cn && m < n)) ++r;
        }
        scf[r] = cn;
        slab[r] = lab[n];
        sbx[r][0] = bx[n][0]; sbx[r][1] = bx[n][1];
        sbx[r][2] = bx[n][2]; sbx[r][3] = bx[n][3];
    }
    __syncthreads();

    // iou > 0.7 bitmask rows
    for (int i = tid; i < NBOX; i += 128) {
        double x1 = sbx[i][0], y1 = sbx[i][1], x2 = sbx[i][2], y2 = sbx[i][3];
        double ai = fmax(x2 - x1, 0.0) * fmax(y2 - y1, 0.0);
        unsigned long long m0 = 0ull, m1 = 0ull;
        for (int j = 0; j < NBOX; ++j) {
            double jx1 = sbx[j][0], jy1 = sbx[j][1], jx2 = sbx[j][2], jy2 = sbx[j][3];
            double xx1 = fmax(x1, jx1), yy1 = fmax(y1, jy1);
            double xx2 = fmin(x2, jx2), yy2 = fmin(y2, jy2);
            double inter = fmax(xx2 - xx1, 0.0) * fmax(yy2 - yy1, 0.0);
            double aj = fmax(jx2 - jx1, 0.0) * fmax(jy2 - jy1, 0.0);
            double uni = ai + aj - inter;
            double iou = (uni > 0.0) ? inter / uni : 0.0;
            if (iou > 0.7) {
                if (j < 64) m0 |= 1ull << j;
                else        m1 |= 1ull << (j - 64);
            }
        }
        suprow[i][0] = m0;
        suprow[i][1] = m1;
    }
    __syncthreads();

    if (tid == 0) {
        unsigned long long k0 = 0ull, k1 = 0ull;
        for (int i = 0; i < NBOX; ++i) {
            if (scf[i] > 0.1) {
                if (i < 64) k0 |= 1ull << i;
                else        k1 |= 1ull << (i - 64);
            }
        }
        for (int i = 0; i < NBOX; ++i) {
            bool ki = (i < 64) ? ((k0 >> i) & 1ull) : ((k1 >> (i - 64)) & 1ull);
            if (!ki) continue;
            unsigned long long g0, g1;
            if (i < 63)       { g0 = (~0ull) << (i + 1); g1 = ~0ull; }
            else if (i == 63) { g0 = 0ull;               g1 = ~0ull; }
            else              { g0 = 0ull;               g1 = (~0ull) << (i - 63); }
            k0 &= ~(suprow[i][0] & g0);
            k1 &= ~(suprow[i][1] & g1);
        }
        int cnt = 0;
        for (int i = 0; i < NBOX && cnt < 10; ++i) {
            bool ki = (i < 64) ? ((k0 >> i) & 1ull) : ((k1 >> (i - 64)) & 1ull);
            if (!ki) continue;
            out_boxes[(size_t)b * 40 + cnt * 4 + 0] = (float)sbx[i][0];
            out_boxes[(size_t)b * 40 + cnt * 4 + 1] = (float)sbx[i][1];
            out_boxes[(size_t)b * 40 + cnt * 4 + 2] = (float)sbx[i][2];
            out_boxes[(size_t)b * 40 + cnt * 4 + 3] = (float)sbx[i][3];
            out_labels[b * 10 + cnt] = (float)slab[i];
            out_confs[b * 10 + cnt]  = (float)scf[i];
            ++cnt;
        }
        for (; cnt < 10; ++cnt) {
            out_boxes[(size_t)b * 40 + cnt * 4 + 0] = 0.0f;
            out_boxes[(size_t)b * 40 + cnt * 4 + 1] = 0.0f;
            out_boxes[(size_t)b * 40 + cnt * 4 + 2] = 0.0f;
            out_boxes[(size_t)b * 40 + cnt * 4 + 3] = 0.0f;
            out_labels[b * 10 + cnt] = 0.0f;
            out_confs[b * 10 + cnt]  = 0.0f;
        }
    }
}

extern "C" void kernel_launch(void* const* d_in, const int* in_sizes, int n_in,
                              void* d_out, int out_size, void* d_ws, size_t ws_size,
                              hipStream_t stream) {
    const float* x      = (const float*)d_in[0];
    const float* conv_w = (const float*)d_in[1];
    const float* conv_b = (const float*)d_in[2];
    const float* fc1_w  = (const float*)d_in[3];
    const float* fc1_b  = (const float*)d_in[4];
    const float* fc2_w  = (const float*)d_in[5];
    const float* fc2_b  = (const float*)d_in[6];

    double* h1 = (double*)d_ws;                       // 256 x 6272
    double* a1 = h1 + (size_t)BATCH * F1IN;           // 256 x 4096 (raw fc1 sums, no bias)
    double* a2 = a1 + (size_t)BATCH * F1OUT;          // 256 x 1470 (raw fc2 sums, no bias)

    float* out_boxes  = (float*)d_out;                // 256*10*4
    float* out_labels = out_boxes + (size_t)BATCH * 40;   // 256*10
    float* out_confs  = out_labels + (size_t)BATCH * 10;  // 256*10

    // zero the atomic-accumulated outputs (graph-capture-legal)
    hipMemsetAsync(a1, 0, (size_t)BATCH * F1OUT * sizeof(double), stream);
    hipMemsetAsync(a2, 0, (size_t)BATCH * F2OUT * sizeof(double), stream);

    conv_kernel<<<dim3(BATCH, 4), 256, 0, stream>>>(x, conv_w, conv_b, h1);

    // FC1: M=256,N=4096,K=6272; BK=16 -> 392 chunks, z=8 (49 each) = 2048 blocks
    fc_splitk_kernel<false, false><<<dim3(4, 64, 8), 256, 0, stream>>>(h1, fc1_w, nullptr, a1, F1OUT, F1IN, 49);

    // FC2: M=256,N=1470,K=4096; BK=16 -> 256 chunks, z=16 (16 each) = 1472 blocks
    // fc1 bias + leaky fused into A-staging
    fc_splitk_kernel<true, true><<<dim3(4, 23, 16), 256, 0, stream>>>(a1, fc2_w, fc1_b, a2, F2OUT, F1OUT, 16);

    // fc2 bias fused into decode's sigmoid
    decode_nms_kernel<<<BATCH, 128, 0, stream>>>(a2, fc2_b, out_boxes, out_labels, out_confs);
}

// Round 6
// 1187.121 us; speedup vs baseline: 1.9373x; 1.2319x over previous
//
#include <hip/hip_runtime.h>
#include <math.h>

#define BATCH 256
#define CIN 1280
#define COUT 128
#define F1IN 6272
#define F1OUT 4096
#define F2OUT 1470
#define NBOX 98

// ---------------------------------------------------------------------------
// Stage 1 (v5): subsample + 1x1 conv as a REAL GEMM, reusing the verified v4
// FC structure. C[o][n] = sum_c W[o][c] * X[n][c],  n = b*49 + s (s = si*7+sj),
// X gathered from x[b][c][2si][2sj]. M=128, N=12544, K=1280.
// 64x64 tile, 4x4 micro, kk-major LDS [16][66] (conflict-free reads, proven
// by v4 counters: 1.8e8 -> 1.3e7 conflicts). Direct store + bias (no atomics),
// c ascending -> bit-identical summation order to v4's conv.
// Old conv inner loop was 0.22 FLOP/LDS-byte (8 reads / 7 FMA) -> est ~500us;
// this is 0.5 FLOP/B with 4x fewer LDS instrs per FLOP.
// ---------------------------------------------------------------------------
__global__ __launch_bounds__(256) void conv_gemm_kernel(const float* __restrict__ wA,
                                                        const float* __restrict__ x,
                                                        const float* __restrict__ bias,
                                                        double* __restrict__ h1) {
    __shared__ double As2[16][66];
    __shared__ double Ws2[16][66];

    const int mbase = blockIdx.x * 64;   // o
    const int nbase = blockIdx.y * 64;   // n = b*49+s
    const int tid = threadIdx.x;
    const int tm = tid >> 4;   // 0..15
    const int tn = tid & 15;   // 0..15

    // fixed staged column for the X-gather (one per thread, hoisted)
    const int scol = tid & 63;
    const int sn = nbase + scol;
    const int sb = sn / 49;
    const int ss = sn - 49 * sb;
    const int ssi = ss / 7;
    const int ssj = ss - 7 * ssi;
    const size_t soff = (size_t)sb * (CIN * 196) + ssi * 28 + ssj * 2; // float idx

    double acc[4][4];
#pragma unroll
    for (int i = 0; i < 4; ++i)
#pragma unroll
        for (int j = 0; j < 4; ++j) acc[i][j] = 0.0;

    for (int cb = 0; cb < CIN; cb += 16) {
        __syncthreads();
        // stage conv_w tile (64 o x 16 c), coalesced (16 lanes = 64B run)
        for (int idx = tid; idx < 64 * 16; idx += 256) {
            int r = idx >> 4, kk = idx & 15;
            As2[kk][r] = (double)wA[(size_t)(mbase + r) * CIN + cb + kk];
        }
        // stage X tile (16 c x 64 n): each thread keeps its col, walks kk
        {
            int kk = tid >> 6;
#pragma unroll
            for (int it = 0; it < 4; ++it, kk += 4)
                Ws2[kk][scol] = (double)x[soff + (size_t)(cb + kk) * 196];
        }
        __syncthreads();
        for (int kk = 0; kk < 16; ++kk) {
            double a[4];
            double bw[4];
#pragma unroll
            for (int i = 0; i < 4; ++i) a[i] = As2[kk][tm + 16 * i];
#pragma unroll
            for (int j = 0; j < 4; ++j) bw[j] = Ws2[kk][tn + 16 * j];
#pragma unroll
            for (int i = 0; i < 4; ++i)
#pragma unroll
                for (int j = 0; j < 4; ++j)
                    acc[i][j] = fma(a[i], bw[j], acc[i][j]);
        }
    }

    // epilogue: h1[b*6272 + o*49 + s] = acc + bias[o]
    int outoff[4];
#pragma unroll
    for (int j = 0; j < 4; ++j) {
        int n = nbase + tn + 16 * j;
        int b = n / 49;
        int s = n - 49 * b;
        outoff[j] = b * F1IN + s;
    }
#pragma unroll
    for (int i = 0; i < 4; ++i) {
        int m = mbase + tm + 16 * i;
        double bv = (double)bias[m];
#pragma unroll
        for (int j = 0; j < 4; ++j)
            h1[(size_t)outoff[j] + (size_t)m * 49] = acc[i][j] + bv;
    }
}

// ---------------------------------------------------------------------------
// FC GEMM split-K (NT): partial C[m][n] += sum_{k in chunk} A[m][k]*W[n][k]
// v5: micro 8x4 (tile 128x64). v4 counters showed LDS-pipe-bound (VALUBusy 43%,
// conflicts fixed): 4x4 = 0.5 FLOP/LDS-byte; 8x4 = 0.67 and -33% LDS instrs
// per FLOP. Same proven kk-major conflict-free read pattern:
//   A-read As2[kk][tm+16i]: 4 distinct banks/wave (16-lane broadcast)
//   W-read Ws2[kk][tn+16j]: 16 distinct banks (4-lane broadcast)
// As2 pad 130 -> bank shift 4/kk-row. LDS 24.5KB -> 6 blocks/CU cap.
// FC1 grid z=8 -> 4 blocks/CU (16 waves); VGPR ~115 (not binding).
// ---------------------------------------------------------------------------
template <bool NCHECK, bool AFUSE>
__global__ __launch_bounds__(256) void fc_splitk_kernel(const double* __restrict__ A,
                                                        const float* __restrict__ W,
                                                        const float* __restrict__ abias,
                                                        double* __restrict__ C,
                                                        int N, int K, int kchunks_per_slice) {
    __shared__ double As2[16][130];
    __shared__ double Ws2[16][66];

    const int mbase = blockIdx.x * 128;
    const int nbase = blockIdx.y * 64;
    const int kb0 = blockIdx.z * kchunks_per_slice * 16;
    const int kb1 = kb0 + kchunks_per_slice * 16;
    const int tid = threadIdx.x;
    const int tm = tid >> 4;   // 0..15 -> rows tm + 16*i, i=0..7
    const int tn = tid & 15;   // 0..15 -> cols tn + 16*j, j=0..3

    double acc[8][4];
#pragma unroll
    for (int i = 0; i < 8; ++i)
#pragma unroll
        for (int j = 0; j < 4; ++j) acc[i][j] = 0.0;

    for (int kb = kb0; kb < kb1; kb += 16) {
        __syncthreads();
        // stage A (128 rows x 16 kk), kk-major, coalesced
        for (int idx = tid; idx < 128 * 16; idx += 256) {
            int r = idx >> 4, kk = idx & 15;
            double v = A[(size_t)(mbase + r) * K + kb + kk];
            if (AFUSE) {
                v += (double)abias[kb + kk];
                v = (v >= 0.0) ? v : 0.1 * v;
            }
            As2[kk][r] = v;
        }
        // stage W (64 cols x 16 kk), kk-major, cvt once
        for (int idx = tid; idx < 64 * 16; idx += 256) {
            int c = idx >> 4, kk = idx & 15;
            int n = nbase + c;
            Ws2[kk][c] = (!NCHECK || n < N) ? (double)W[(size_t)n * K + kb + kk] : 0.0;
        }
        __syncthreads();
        for (int kk = 0; kk < 16; ++kk) {
            double a[8];
            double bw[4];
#pragma unroll
            for (int i = 0; i < 8; ++i) a[i] = As2[kk][tm + 16 * i];
#pragma unroll
            for (int j = 0; j < 4; ++j) bw[j] = Ws2[kk][tn + 16 * j];
#pragma unroll
            for (int i = 0; i < 8; ++i)
#pragma unroll
                for (int j = 0; j < 4; ++j)
                    acc[i][j] = fma(a[i], bw[j], acc[i][j]);
        }
    }

#pragma unroll
    for (int i = 0; i < 8; ++i) {
        int m = mbase + tm + 16 * i;
#pragma unroll
        for (int j = 0; j < 4; ++j) {
            int n = nbase + tn + 16 * j;
            if (!NCHECK || n < N)
                atomicAdd(&C[(size_t)m * N + n], acc[i][j]);
        }
    }
}

// ---------------------------------------------------------------------------
// Stage 4: fc2 bias + sigmoid + decode + stable sort + greedy NMS + top-10.
// One block / image. (unchanged)
// ---------------------------------------------------------------------------
__global__ __launch_bounds__(128) void decode_nms_kernel(const double* __restrict__ Z,
                                                         const float* __restrict__ fc2b,
                                                         float* __restrict__ out_boxes,
                                                         float* __restrict__ out_labels,
                                                         float* __restrict__ out_confs) {
    const int b = blockIdx.x;
    const int tid = threadIdx.x;

    __shared__ double sAll[F2OUT];
    __shared__ double bx[NBOX][4];
    __shared__ double cf[NBOX];
    __shared__ int lab[NBOX];
    __shared__ double sbx[NBOX][4];
    __shared__ double scf[NBOX];
    __shared__ int slab[NBOX];
    __shared__ unsigned long long suprow[NBOX][2];

    const double* z = Z + (size_t)b * F2OUT;
    for (int i = tid; i < F2OUT; i += 128) {
        double v = z[i] + (double)fc2b[i];
        sAll[i] = 1.0 / (1.0 + exp(-v));
    }
    __syncthreads();

    // decode 98 boxes + labels
    for (int n = tid; n < NBOX; n += 128) {
        int gi = n / 14;
        int gj = (n % 14) >> 1;
        double cx = sAll[4 * n + 0] * 64.0 + 64.0 * (double)gi;
        double cy = sAll[4 * n + 1] * 64.0 + 64.0 * (double)gj;
        double w  = sAll[4 * n + 2] * 448.0;
        double hh = sAll[4 * n + 3] * 448.0;
        double x1 = cx - 0.5 * w,  y1 = cy - 0.5 * hh;
        double x2 = cx + 0.5 * w,  y2 = cy + 0.5 * hh;
        x1 = x1 < 0.0 ? 0.0 : (x1 > 448.0 ? 448.0 : x1);
        y1 = y1 < 0.0 ? 0.0 : (y1 > 448.0 ? 448.0 : y1);
        x2 = x2 < 0.0 ? 0.0 : (x2 > 448.0 ? 448.0 : x2);
        y2 = y2 < 0.0 ? 0.0 : (y2 > 448.0 ? 448.0 : y2);
        bx[n][0] = x1; bx[n][1] = y1; bx[n][2] = x2; bx[n][3] = y2;
        cf[n] = sAll[392 + n];
        int cell = n >> 1;
        double best = sAll[490 + cell * 20];
        int bl = 0;
        for (int c = 1; c < 20; ++c) {
            double v = sAll[490 + cell * 20 + c];
            if (v > best) { best = v; bl = c; }
        }
        lab[n] = bl;
    }
    __syncthreads();

    // stable descending sort by conf via rank counting
    for (int n = tid; n < NBOX; n += 128) {
        double cn = cf[n];
        int r = 0;
        for (int m = 0; m < NBOX; ++m) {
            double cm = cf[m];
            if (cm > cn || (cm == cn && m < n)) ++r;
        }
        scf[r] = cn;
        slab[r] = lab[n];
        sbx[r][0] = bx[n][0]; sbx[r][1] = bx[n][1];
        sbx[r][2] = bx[n][2]; sbx[r][3] = bx[n][3];
    }
    __syncthreads();

    // iou > 0.7 bitmask rows
    for (int i = tid; i < NBOX; i += 128) {
        double x1 = sbx[i][0], y1 = sbx[i][1], x2 = sbx[i][2], y2 = sbx[i][3];
        double ai = fmax(x2 - x1, 0.0) * fmax(y2 - y1, 0.0);
        unsigned long long m0 = 0ull, m1 = 0ull;
        for (int j = 0; j < NBOX; ++j) {
            double jx1 = sbx[j][0], jy1 = sbx[j][1], jx2 = sbx[j][2], jy2 = sbx[j][3];
            double xx1 = fmax(x1, jx1), yy1 = fmax(y1, jy1);
            double xx2 = fmin(x2, jx2), yy2 = fmin(y2, jy2);
            double inter = fmax(xx2 - xx1, 0.0) * fmax(yy2 - yy1, 0.0);
            double aj = fmax(jx2 - jx1, 0.0) * fmax(jy2 - jy1, 0.0);
            double uni = ai + aj - inter;
            double iou = (uni > 0.0) ? inter / uni : 0.0;
            if (iou > 0.7) {
                if (j < 64) m0 |= 1ull << j;
                else        m1 |= 1ull << (j - 64);
            }
        }
        suprow[i][0] = m0;
        suprow[i][1] = m1;
    }
    __syncthreads();

    if (tid == 0) {
        unsigned long long k0 = 0ull, k1 = 0ull;
        for (int i = 0; i < NBOX; ++i) {
            if (scf[i] > 0.1) {
                if (i < 64) k0 |= 1ull << i;
                else        k1 |= 1ull << (i - 64);
            }
        }
        for (int i = 0; i < NBOX; ++i) {
            bool ki = (i < 64) ? ((k0 >> i) & 1ull) : ((k1 >> (i - 64)) & 1ull);
            if (!ki) continue;
            unsigned long long g0, g1;
            if (i < 63)       { g0 = (~0ull) << (i + 1); g1 = ~0ull; }
            else if (i == 63) { g0 = 0ull;               g1 = ~0ull; }
            else              { g0 = 0ull;               g1 = (~0ull) << (i - 63); }
            k0 &= ~(suprow[i][0] & g0);
            k1 &= ~(suprow[i][1] & g1);
        }
        int cnt = 0;
        for (int i = 0; i < NBOX && cnt < 10; ++i) {
            bool ki = (i < 64) ? ((k0 >> i) & 1ull) : ((k1 >> (i - 64)) & 1ull);
            if (!ki) continue;
            out_boxes[(size_t)b * 40 + cnt * 4 + 0] = (float)sbx[i][0];
            out_boxes[(size_t)b * 40 + cnt * 4 + 1] = (float)sbx[i][1];
            out_boxes[(size_t)b * 40 + cnt * 4 + 2] = (float)sbx[i][2];
            out_boxes[(size_t)b * 40 + cnt * 4 + 3] = (float)sbx[i][3];
            out_labels[b * 10 + cnt] = (float)slab[i];
            out_confs[b * 10 + cnt]  = (float)scf[i];
            ++cnt;
        }
        for (; cnt < 10; ++cnt) {
            out_boxes[(size_t)b * 40 + cnt * 4 + 0] = 0.0f;
            out_boxes[(size_t)b * 40 + cnt * 4 + 1] = 0.0f;
            out_boxes[(size_t)b * 40 + cnt * 4 + 2] = 0.0f;
            out_boxes[(size_t)b * 40 + cnt * 4 + 3] = 0.0f;
            out_labels[b * 10 + cnt] = 0.0f;
            out_confs[b * 10 + cnt]  = 0.0f;
        }
    }
}

extern "C" void kernel_launch(void* const* d_in, const int* in_sizes, int n_in,
                              void* d_out, int out_size, void* d_ws, size_t ws_size,
                              hipStream_t stream) {
    const float* x      = (const float*)d_in[0];
    const float* conv_w = (const float*)d_in[1];
    const float* conv_b = (const float*)d_in[2];
    const float* fc1_w  = (const float*)d_in[3];
    const float* fc1_b  = (const float*)d_in[4];
    const float* fc2_w  = (const float*)d_in[5];
    const float* fc2_b  = (const float*)d_in[6];

    double* h1 = (double*)d_ws;                       // 256 x 6272
    double* a1 = h1 + (size_t)BATCH * F1IN;           // 256 x 4096 (raw fc1 sums, no bias)
    double* a2 = a1 + (size_t)BATCH * F1OUT;          // 256 x 1470 (raw fc2 sums, no bias)

    float* out_boxes  = (float*)d_out;                // 256*10*4
    float* out_labels = out_boxes + (size_t)BATCH * 40;   // 256*10
    float* out_confs  = out_labels + (size_t)BATCH * 10;  // 256*10

    // zero the atomic-accumulated outputs (graph-capture-legal)
    hipMemsetAsync(a1, 0, (size_t)BATCH * F1OUT * sizeof(double), stream);
    hipMemsetAsync(a2, 0, (size_t)BATCH * F2OUT * sizeof(double), stream);

    // conv as GEMM: M=128(o), N=12544(b*49+s), K=1280(c); direct store + bias
    conv_gemm_kernel<<<dim3(2, 196), 256, 0, stream>>>(conv_w, x, conv_b, h1);

    // FC1: M=256,N=4096,K=6272; tile 128x64, BK=16 -> 392 chunks, z=8 (49 each)
    fc_splitk_kernel<false, false><<<dim3(2, 64, 8), 256, 0, stream>>>(h1, fc1_w, nullptr, a1, F1OUT, F1IN, 49);

    // FC2: M=256,N=1470,K=4096; tile 128x64, BK=16 -> 256 chunks, z=16 (16 each)
    // fc1 bias + leaky fused into A-staging
    fc_splitk_kernel<true, true><<<dim3(2, 23, 16), 256, 0, stream>>>(a1, fc2_w, fc1_b, a2, F2OUT, F1OUT, 16);

    // fc2 bias fused into decode's sigmoid
    decode_nms_kernel<<<BATCH, 128, 0, stream>>>(a2, fc2_b, out_boxes, out_labels, out_confs);
}